// Round 2
// baseline (1587.379 us; speedup 1.0000x reference)
//
#include <hip/hip_runtime.h>
#include <hip/hip_bf16.h>

#define S_LEN 4096
#define D_MODEL 512
#define DKV 64
#define B_N 4

typedef __hip_bfloat16 bf16;

__device__ __forceinline__ float b2f(bf16 v) { return __bfloat162float(v); }

// ---------------------------------------------------------------------------
// Kernel 0: dtype detect. On little-endian, if the buffer is fp32, bf16-view
// EVEN indices alias the low mantissa halfword -> random exponent -> ~48% of
// samples have |v|>64 or NaN. If the buffer is genuinely bf16 (x ~ N(0,1)),
// every sample is sane. flag=1 -> fp32 buffers, flag=0 -> bf16 buffers.
// ---------------------------------------------------------------------------
__global__ __launch_bounds__(64) void detect_kernel(const void* x, int* flag) {
    const int lane = threadIdx.x;
    const bf16* xb = (const bf16*)x;
    int bad = 0;
    for (int k = lane; k < 4096; k += 64) {
        float v = fabsf(b2f(xb[2 * k]));     // even halfword
        if (!(v < 64.f)) bad++;              // catches NaN too
    }
    #pragma unroll
    for (int off = 32; off >= 1; off >>= 1) bad += __shfl_xor(bad, off);
    if (lane == 0) *flag = (bad > 100) ? 1 : 0;
}

// ---------------------------------------------------------------------------
// Kernel 1: fused Q/K/V projection. One block per (b,s) row, 192 threads:
// [0,64)->Q, [64,128)->K, [128,192)->V. x row staged in LDS. Wave-uniform
// dtype branch (explicit if: no speculative wrong-dtype OOB loads).
// ---------------------------------------------------------------------------
__global__ __launch_bounds__(192) void qkv_kernel(
    const void* __restrict__ x,
    const void* __restrict__ Wq, const void* __restrict__ bq,
    const void* __restrict__ Wk, const void* __restrict__ bk,
    const void* __restrict__ Wv, const void* __restrict__ bv,
    float* __restrict__ Q, float* __restrict__ K, float* __restrict__ V,
    const int* __restrict__ flag)
{
    const int row = blockIdx.x;
    const int tid = threadIdx.x;
    const int f32 = *flag;
    __shared__ float xs[D_MODEL];

    if (f32) {
        const float* xr = (const float*)x + (size_t)row * D_MODEL;
        for (int idx = tid; idx < D_MODEL; idx += 192) xs[idx] = xr[idx];
    } else {
        const bf16* xr = (const bf16*)x + (size_t)row * D_MODEL;
        for (int idx = tid; idx < D_MODEL; idx += 192) xs[idx] = b2f(xr[idx]);
    }
    __syncthreads();

    const int g = tid >> 6;              // 0=Q 1=K 2=V
    const int c = tid & 63;
    const void* W    = (g == 0) ? Wq : (g == 1) ? Wk : Wv;
    const void* bias = (g == 0) ? bq : (g == 1) ? bk : bv;
    float* dst       = (g == 0) ? Q  : (g == 1) ? K  : V;

    float sum = 0.f;
    if (f32) {
        const float* Wf = (const float*)W;
        #pragma unroll 8
        for (int d = 0; d < D_MODEL; ++d) sum += xs[d] * Wf[d * DKV + c];
        sum += ((const float*)bias)[c];
    } else {
        const bf16* Wb = (const bf16*)W;
        #pragma unroll 8
        for (int d = 0; d < D_MODEL; ++d) sum += xs[d] * b2f(Wb[d * DKV + c]);
        sum += b2f(((const bf16*)bias)[c]);
    }
    dst[(size_t)row * DKV + c] = sum;
}

// ---------------------------------------------------------------------------
// Kernel 2: causal flash attention, one wave per query row. Q/K/V are fp32
// in workspace (dtype-independent). Lane l scores key base+l (float4 K
// loads), wave-shuffle online softmax, p via LDS, lane d accumulates output
// dim d with coalesced V column reads.
// ---------------------------------------------------------------------------
__global__ __launch_bounds__(64) void attn_kernel(
    const float* __restrict__ Q, const float* __restrict__ K,
    const float* __restrict__ V, float* __restrict__ O)
{
    const int row  = blockIdx.x;
    const int b    = row >> 12;
    const int i    = row & (S_LEN - 1);
    const int lane = threadIdx.x;

    __shared__ float q_s[DKV];
    __shared__ float p_s[DKV];

    const float* Kb = K + (size_t)b * S_LEN * DKV;
    const float* Vb = V + (size_t)b * S_LEN * DKV;

    q_s[lane] = Q[(size_t)row * DKV + lane];
    __syncthreads();

    float m = -INFINITY, l = 0.f, acc = 0.f;
    const float scale = 0.125f;          // 1/sqrt(64)

    for (int base = 0; base <= i; base += 64) {
        const int j = base + lane;
        float s = -INFINITY;
        if (j <= i) {
            const float4* kr = (const float4*)(Kb + (size_t)j * DKV);
            float sum = 0.f;
            #pragma unroll
            for (int d4 = 0; d4 < 16; ++d4) {
                float4 kv = kr[d4];
                sum += q_s[d4*4+0]*kv.x + q_s[d4*4+1]*kv.y
                     + q_s[d4*4+2]*kv.z + q_s[d4*4+3]*kv.w;
            }
            s = sum * scale;
        }
        float cmax = s;
        #pragma unroll
        for (int off = 32; off >= 1; off >>= 1)
            cmax = fmaxf(cmax, __shfl_xor(cmax, off));
        const float m_new = fmaxf(m, cmax);
        const float p     = (j <= i) ? __expf(s - m_new) : 0.f;
        const float alpha = __expf(m - m_new);   // m=-inf first iter -> 0
        float psum = p;
        #pragma unroll
        for (int off = 32; off >= 1; off >>= 1)
            psum += __shfl_xor(psum, off);
        l = l * alpha + psum;
        acc *= alpha;

        p_s[lane] = p;
        __syncthreads();
        const float* vp = Vb + (size_t)base * DKV + lane;
        #pragma unroll 8
        for (int jj = 0; jj < 64; ++jj)
            acc += p_s[jj] * vp[jj * DKV];   // masked keys have p=0
        __syncthreads();
        m = m_new;
    }
    O[(size_t)row * DKV + lane] = acc / l;
}

// ---------------------------------------------------------------------------
// Kernel 3: output projection (16384 x 64) @ (64 x 512) + bias.
// One block per row, 256 threads, 2 output dims/thread; Wo reads coalesced.
// Output dtype follows the detected input dtype.
// ---------------------------------------------------------------------------
__global__ __launch_bounds__(256) void proj_kernel(
    const float* __restrict__ A, const void* __restrict__ Wo,
    const void* __restrict__ bo, void* __restrict__ out,
    const int* __restrict__ flag)
{
    const int row = blockIdx.x;
    const int tid = threadIdx.x;
    const int f32 = *flag;
    __shared__ float as[DKV];
    if (tid < DKV) as[tid] = A[(size_t)row * DKV + tid];
    __syncthreads();

    if (f32) {
        const float* Wf = (const float*)Wo;
        #pragma unroll
        for (int rep = 0; rep < 2; ++rep) {
            const int o = rep * 256 + tid;
            float sum = 0.f;
            #pragma unroll 8
            for (int v = 0; v < DKV; ++v) sum += as[v] * Wf[v * D_MODEL + o];
            sum += ((const float*)bo)[o];
            ((float*)out)[(size_t)row * D_MODEL + o] = sum;
        }
    } else {
        const bf16* Wb = (const bf16*)Wo;
        #pragma unroll
        for (int rep = 0; rep < 2; ++rep) {
            const int o = rep * 256 + tid;
            float sum = 0.f;
            #pragma unroll 8
            for (int v = 0; v < DKV; ++v) sum += as[v] * b2f(Wb[v * D_MODEL + o]);
            sum += b2f(((const bf16*)bo)[o]);
            ((bf16*)out)[(size_t)row * D_MODEL + o] = __float2bfloat16(sum);
        }
    }
}

extern "C" void kernel_launch(void* const* d_in, const int* in_sizes, int n_in,
                              void* d_out, int out_size, void* d_ws, size_t ws_size,
                              hipStream_t stream) {
    const void* x  = d_in[0];
    const void* Wq = d_in[1];
    const void* bq = d_in[2];
    const void* Wk = d_in[3];
    const void* bk = d_in[4];
    const void* Wv = d_in[5];
    const void* bv = d_in[6];
    const void* Wo = d_in[7];
    const void* bo = d_in[8];

    const int rows = B_N * S_LEN;            // 16384
    int*   flag = (int*)d_ws;                // 4 B flag at offset 0
    float* Q = (float*)((char*)d_ws + 256);  // 256B-aligned arrays
    float* K = Q + (size_t)rows * DKV;
    float* V = K + (size_t)rows * DKV;
    float* A = V + (size_t)rows * DKV;       // total ~16.8 MB + 256 B

    detect_kernel<<<1, 64, 0, stream>>>(x, flag);
    qkv_kernel<<<rows, 192, 0, stream>>>(x, Wq, bq, Wk, bk, Wv, bv, Q, K, V, flag);
    attn_kernel<<<rows, 64, 0, stream>>>(Q, K, V, A);
    proj_kernel<<<rows, 256, 0, stream>>>(A, Wo, bo, d_out, flag);
}

// Round 3
// 509.676 us; speedup vs baseline: 3.1145x; 3.1145x over previous
//
#include <hip/hip_runtime.h>
#include <hip/hip_bf16.h>

#define S_LEN 4096
#define D_MODEL 512
#define DKV 64
#define B_N 4
#define STR 72   // LDS row stride (elems): 144 B = 16B-aligned, breaks 16-way bank conflicts

typedef __hip_bfloat16 bf16;
typedef __attribute__((ext_vector_type(8))) short short8;   // 8 bf16 (4 VGPRs)
typedef __attribute__((ext_vector_type(4))) float floatx4;  // MFMA C/D

#define MFMA(a, b, c) __builtin_amdgcn_mfma_f32_16x16x32_bf16(a, b, c, 0, 0, 0)

__device__ __forceinline__ float b2f(bf16 v) { return __bfloat162float(v); }

// ---------------------------------------------------------------------------
// Kernel 0: dtype detect (kept from R2 — it picked the right path).
// ---------------------------------------------------------------------------
__global__ __launch_bounds__(64) void detect_kernel(const void* x, int* flag) {
    const int lane = threadIdx.x;
    const bf16* xb = (const bf16*)x;
    int bad = 0;
    for (int k = lane; k < 4096; k += 64) {
        float v = fabsf(b2f(xb[2 * k]));
        if (!(v < 64.f)) bad++;
    }
    #pragma unroll
    for (int off = 32; off >= 1; off >>= 1) bad += __shfl_xor(bad, off);
    if (lane == 0) *flag = (bad > 100) ? 1 : 0;
}

// ---------------------------------------------------------------------------
// Kernel 1: fused Q/K/V projection -> bf16 Q,K (row-major) + bf16 V^T.
// ---------------------------------------------------------------------------
__global__ __launch_bounds__(192) void qkv_kernel(
    const void* __restrict__ x,
    const void* __restrict__ Wq, const void* __restrict__ bq,
    const void* __restrict__ Wk, const void* __restrict__ bk,
    const void* __restrict__ Wv, const void* __restrict__ bv,
    bf16* __restrict__ Qb, bf16* __restrict__ Kb, bf16* __restrict__ Vt,
    const int* __restrict__ flag)
{
    const int row = blockIdx.x;
    const int tid = threadIdx.x;
    const int f32 = *flag;
    __shared__ float xs[D_MODEL];

    if (f32) {
        const float* xr = (const float*)x + (size_t)row * D_MODEL;
        for (int idx = tid; idx < D_MODEL; idx += 192) xs[idx] = xr[idx];
    } else {
        const bf16* xr = (const bf16*)x + (size_t)row * D_MODEL;
        for (int idx = tid; idx < D_MODEL; idx += 192) xs[idx] = b2f(xr[idx]);
    }
    __syncthreads();

    const int g = tid >> 6;              // 0=Q 1=K 2=V
    const int c = tid & 63;
    const void* W    = (g == 0) ? Wq : (g == 1) ? Wk : Wv;
    const void* bias = (g == 0) ? bq : (g == 1) ? bk : bv;

    float sum = 0.f;
    if (f32) {
        const float* Wf = (const float*)W;
        #pragma unroll 8
        for (int d = 0; d < D_MODEL; ++d) sum += xs[d] * Wf[d * DKV + c];
        sum += ((const float*)bias)[c];
    } else {
        const bf16* Wb = (const bf16*)W;
        #pragma unroll 8
        for (int d = 0; d < D_MODEL; ++d) sum += xs[d] * b2f(Wb[d * DKV + c]);
        sum += b2f(((const bf16*)bias)[c]);
    }

    const bf16 o = __float2bfloat16(sum);
    if (g == 0)      Qb[(size_t)row * DKV + c] = o;
    else if (g == 1) Kb[(size_t)row * DKV + c] = o;
    else {
        const int b = row >> 12, s = row & (S_LEN - 1);
        Vt[((size_t)b * DKV + c) * S_LEN + s] = o;   // transposed for PV B-frag
    }
}

// ---------------------------------------------------------------------------
// Kernel 2: MFMA flash attention. BM=32 Q-rows/block, 4 waves, BN=64 keys/iter.
// Wave w: rows 16*(w&1)..+16, cols (keys or vdims) 32*(w>>1)..+32 (2 tiles).
// Layouts (verified, guide §3/m120): C/D col=lane&15,row=quad*4+reg;
// A[m=lane&15][k=quad*8+j]; B[k=quad*8+j][n=lane&15].
// ---------------------------------------------------------------------------
__global__ __launch_bounds__(256) void attn_mfma(
    const bf16* __restrict__ Qg, const bf16* __restrict__ Kg,
    const bf16* __restrict__ Vtg, float* __restrict__ O)
{
    const int bid = blockIdx.x;
    const int b = bid >> 7;
    const int t = 127 - (bid & 127);     // longest tiles dispatch first
    const int rowBase = t * 32;
    const int tid = threadIdx.x;
    const int lane = tid & 63;
    const int w  = tid >> 6;
    const int wr = w & 1;
    const int wc = w >> 1;
    const int quad = lane >> 4;
    const int l15  = lane & 15;

    __shared__ bf16 Kl[64 * STR];        // [key][dim]
    __shared__ bf16 Vl[64 * STR];        // [vdim][key]
    __shared__ bf16 Pl[32 * STR];        // [row][key]; doubles as Q staging
    __shared__ float redm[2][32];
    __shared__ float reds[2][32];

    const bf16* Qb = Qg + ((size_t)b * S_LEN + rowBase) * DKV;
    const bf16* Kb = Kg + (size_t)b * S_LEN * DKV;
    const bf16* Vb = Vtg + (size_t)b * DKV * S_LEN;

    // stage Q tile (32x64) into Pl, load A-fragments once
    {
        const int r = tid >> 3, d0 = (tid & 7) * 8;
        *(uint4*)&Pl[r * STR + d0] = *(const uint4*)&Qb[r * DKV + d0];
    }
    __syncthreads();
    short8 qf0, qf1;
    {
        const int qoff = (wr * 16 + l15) * STR + quad * 8;
        qf0 = *(const short8*)&Pl[qoff];
        qf1 = *(const short8*)&Pl[qoff + 32];
    }

    floatx4 acc0 = {0.f, 0.f, 0.f, 0.f}, acc1 = {0.f, 0.f, 0.f, 0.f};
    float m_run[4], l_run[4];
    #pragma unroll
    for (int r = 0; r < 4; ++r) { m_run[r] = -1e30f; l_run[r] = 0.f; }

    const int ktMax = (rowBase + 31) >> 6;
    const float cs = 0.18033688f;        // 0.125 * log2(e): exp2 domain

    for (int kt = 0; kt <= ktMax; ++kt) {
        __syncthreads();                 // prior-iter LDS reads (and Q-frag reads) done
        {   // stage K tile + Vt tile (8 KB each), 2x16B per thread each
            const int kk = tid >> 2, d0 = (tid & 3) * 16;
            const uint4* ks = (const uint4*)&Kb[((size_t)(kt * 64 + kk)) * DKV + d0];
            uint4* kd = (uint4*)&Kl[kk * STR + d0];
            kd[0] = ks[0]; kd[1] = ks[1];
            const uint4* vs = (const uint4*)&Vb[(size_t)kk * S_LEN + kt * 64 + d0];
            uint4* vd = (uint4*)&Vl[kk * STR + d0];
            vd[0] = vs[0]; vd[1] = vs[1];
        }
        __syncthreads();

        // S = Q K^T : two 16x16 tiles per wave (K=64 over 2 MFMAs each)
        floatx4 s0 = {0.f, 0.f, 0.f, 0.f}, s1 = {0.f, 0.f, 0.f, 0.f};
        {
            const int qk = quad * 8;
            const int key0 = (wc * 32 + l15) * STR;
            const int key1 = key0 + 16 * STR;
            short8 b00 = *(const short8*)&Kl[key0 + qk];
            short8 b01 = *(const short8*)&Kl[key0 + qk + 32];
            short8 b10 = *(const short8*)&Kl[key1 + qk];
            short8 b11 = *(const short8*)&Kl[key1 + qk + 32];
            s0 = MFMA(qf0, b00, s0);
            s0 = MFMA(qf1, b01, s0);
            s1 = MFMA(qf0, b10, s1);
            s1 = MFMA(qf1, b11, s1);
        }
        #pragma unroll
        for (int r = 0; r < 4; ++r) { s0[r] *= cs; s1[r] *= cs; }
        if (kt == ktMax) {               // causal mask, uniform branch
            const int rowg = rowBase + wr * 16 + quad * 4;
            const int k0g = kt * 64 + wc * 32 + l15;
            #pragma unroll
            for (int r = 0; r < 4; ++r) {
                if (k0g > rowg + r)      s0[r] = -1e30f;
                if (k0g + 16 > rowg + r) s1[r] = -1e30f;
            }
        }
        // per-row max over this wave's 32 cols (16-lane butterfly)
        float m4[4];
        #pragma unroll
        for (int r = 0; r < 4; ++r) m4[r] = fmaxf(s0[r], s1[r]);
        #pragma unroll
        for (int off = 1; off < 16; off <<= 1) {
            #pragma unroll
            for (int r = 0; r < 4; ++r) m4[r] = fmaxf(m4[r], __shfl_xor(m4[r], off));
        }
        if (l15 == 0) {
            #pragma unroll
            for (int r = 0; r < 4; ++r) redm[wc][wr * 16 + quad * 4 + r] = m4[r];
        }
        __syncthreads();
        float alpha[4], mnew[4];
        #pragma unroll
        for (int r = 0; r < 4; ++r) {
            const int row = wr * 16 + quad * 4 + r;
            const float mm = fmaxf(redm[0][row], redm[1][row]);
            mnew[r] = fmaxf(m_run[r], mm);
            alpha[r] = exp2f(m_run[r] - mnew[r]);   // -1e30 first iter -> 0
            m_run[r] = mnew[r];
        }
        float ps[4];
        #pragma unroll
        for (int r = 0; r < 4; ++r) {
            const float p0 = exp2f(s0[r] - mnew[r]);
            const float p1 = exp2f(s1[r] - mnew[r]);
            s0[r] = p0; s1[r] = p1;
            ps[r] = p0 + p1;
        }
        #pragma unroll
        for (int off = 1; off < 16; off <<= 1) {
            #pragma unroll
            for (int r = 0; r < 4; ++r) ps[r] += __shfl_xor(ps[r], off);
        }
        if (l15 == 0) {
            #pragma unroll
            for (int r = 0; r < 4; ++r) reds[wc][wr * 16 + quad * 4 + r] = ps[r];
        }
        // rescale O-acc, write P (bf16) to LDS
        #pragma unroll
        for (int r = 0; r < 4; ++r) {
            acc0[r] *= alpha[r]; acc1[r] *= alpha[r];
            const int poff = (wr * 16 + quad * 4 + r) * STR + wc * 32 + l15;
            Pl[poff]      = __float2bfloat16(s0[r]);
            Pl[poff + 16] = __float2bfloat16(s1[r]);
        }
        __syncthreads();
        #pragma unroll
        for (int r = 0; r < 4; ++r) {
            const int row = wr * 16 + quad * 4 + r;
            l_run[r] = l_run[r] * alpha[r] + reds[0][row] + reds[1][row];
        }
        // O += P V : two 16x16 tiles per wave (K=64 keys over 2 MFMAs each)
        {
            const int pk = quad * 8;
            const int prow = (wr * 16 + l15) * STR;
            const int v0 = (wc * 32 + l15) * STR;
            const int v1 = v0 + 16 * STR;
            short8 pa0 = *(const short8*)&Pl[prow + pk];
            short8 pa1 = *(const short8*)&Pl[prow + pk + 32];
            short8 vb00 = *(const short8*)&Vl[v0 + pk];
            short8 vb01 = *(const short8*)&Vl[v0 + pk + 32];
            short8 vb10 = *(const short8*)&Vl[v1 + pk];
            short8 vb11 = *(const short8*)&Vl[v1 + pk + 32];
            acc0 = MFMA(pa0, vb00, acc0);
            acc0 = MFMA(pa1, vb01, acc0);
            acc1 = MFMA(pa0, vb10, acc1);
            acc1 = MFMA(pa1, vb11, acc1);
        }
    }
    // epilogue: normalize, store fp32 O[row][vdim]
    #pragma unroll
    for (int r = 0; r < 4; ++r) {
        const float inv = 1.0f / l_run[r];
        const int row = rowBase + wr * 16 + quad * 4 + r;
        float* op = O + ((size_t)b * S_LEN + row) * DKV + wc * 32 + l15;
        op[0]  = acc0[r] * inv;
        op[16] = acc1[r] * inv;
    }
}

// ---------------------------------------------------------------------------
// Kernel 3: output projection (16384 x 64) @ (64 x 512) + bias.
// ---------------------------------------------------------------------------
__global__ __launch_bounds__(256) void proj_kernel(
    const float* __restrict__ A, const void* __restrict__ Wo,
    const void* __restrict__ bo, void* __restrict__ out,
    const int* __restrict__ flag)
{
    const int row = blockIdx.x;
    const int tid = threadIdx.x;
    const int f32 = *flag;
    __shared__ float as[DKV];
    if (tid < DKV) as[tid] = A[(size_t)row * DKV + tid];
    __syncthreads();

    if (f32) {
        const float* Wf = (const float*)Wo;
        #pragma unroll
        for (int rep = 0; rep < 2; ++rep) {
            const int o = rep * 256 + tid;
            float sum = 0.f;
            #pragma unroll 8
            for (int v = 0; v < DKV; ++v) sum += as[v] * Wf[v * D_MODEL + o];
            sum += ((const float*)bo)[o];
            ((float*)out)[(size_t)row * D_MODEL + o] = sum;
        }
    } else {
        const bf16* Wb = (const bf16*)Wo;
        #pragma unroll
        for (int rep = 0; rep < 2; ++rep) {
            const int o = rep * 256 + tid;
            float sum = 0.f;
            #pragma unroll 8
            for (int v = 0; v < DKV; ++v) sum += as[v] * b2f(Wb[v * D_MODEL + o]);
            sum += b2f(((const bf16*)bo)[o]);
            ((bf16*)out)[(size_t)row * D_MODEL + o] = __float2bfloat16(sum);
        }
    }
}

extern "C" void kernel_launch(void* const* d_in, const int* in_sizes, int n_in,
                              void* d_out, int out_size, void* d_ws, size_t ws_size,
                              hipStream_t stream) {
    const void* x  = d_in[0];
    const void* Wq = d_in[1];
    const void* bq = d_in[2];
    const void* Wk = d_in[3];
    const void* bk = d_in[4];
    const void* Wv = d_in[5];
    const void* bv = d_in[6];
    const void* Wo = d_in[7];
    const void* bo = d_in[8];

    const int rows = B_N * S_LEN;                 // 16384
    int*  flag = (int*)d_ws;
    bf16* Qb = (bf16*)((char*)d_ws + 256);        // 2 MB each
    bf16* Kb = Qb + (size_t)rows * DKV;
    bf16* Vt = Kb + (size_t)rows * DKV;
    float* Oa = (float*)(Vt + (size_t)rows * DKV); // 4 MB fp32

    detect_kernel<<<1, 64, 0, stream>>>(x, flag);
    qkv_kernel<<<rows, 192, 0, stream>>>(x, Wq, bq, Wk, bk, Wv, bv, Qb, Kb, Vt, flag);
    attn_mfma<<<512, 256, 0, stream>>>(Qb, Kb, Vt, Oa);
    proj_kernel<<<rows, 256, 0, stream>>>(Oa, Wo, bo, d_out, flag);
}